// Round 14
// baseline (475.562 us; speedup 1.0000x reference)
//
#include <hip/hip_runtime.h>
#include <math.h>

#define NN 64      // nodes
#define TT 256     // frames
#define FF 13      // input features
#define EE 4032    // edges (complete digraph)
#define PP 128     // pooling channels / GAT1 out
#define HH 128     // hidden

typedef float f32x4 __attribute__((ext_vector_type(4)));
typedef short s16x8 __attribute__((ext_vector_type(8)));
typedef unsigned u32x4 __attribute__((ext_vector_type(4)));

__device__ __forceinline__ float wave_sum64(float v) {
#pragma unroll
  for (int off = 32; off > 0; off >>= 1) v += __shfl_xor(v, off, 64);
  return v;
}
__device__ __forceinline__ float sigm(float x) { return 1.f / (1.f + __expf(-x)); }
__device__ __forceinline__ float tanh_fast(float x) { return 1.f - 2.f / (__expf(2.f * x) + 1.f); }

// ---- DPP / lane helpers (VALU pipe) ----
#define ROTF(x, N) __builtin_bit_cast(float, __builtin_amdgcn_mov_dpp( \
    __builtin_bit_cast(int, x), 0x120 + (N), 0xF, 0xF, true))
__device__ __forceinline__ float rdlane(float v, int l) {
  return __builtin_bit_cast(float, __builtin_amdgcn_readlane(__builtin_bit_cast(int, v), l));
}
__device__ __forceinline__ float allred_max(float v) {
  v = fmaxf(v, ROTF(v, 1)); v = fmaxf(v, ROTF(v, 2));
  v = fmaxf(v, ROTF(v, 4)); v = fmaxf(v, ROTF(v, 8));
  return fmaxf(fmaxf(rdlane(v, 0), rdlane(v, 16)),
               fmaxf(rdlane(v, 32), rdlane(v, 48)));
}
__device__ __forceinline__ float allred_sum(float v) {
  v += ROTF(v, 1); v += ROTF(v, 2); v += ROTF(v, 4); v += ROTF(v, 8);
  return (rdlane(v, 0) + rdlane(v, 16)) + (rdlane(v, 32) + rdlane(v, 48));
}

// fp32 -> bf16 (round-to-nearest-even), plain integer ops
__device__ __forceinline__ unsigned bf16rne(float x) {
  const unsigned u = __builtin_bit_cast(unsigned, x);
  return (u + 0x7FFFu + ((u >> 16) & 1u)) >> 16;
}
__device__ __forceinline__ unsigned pk_bf16(float lo, float hi) {
  return bf16rne(lo) | (bf16rne(hi) << 16);
}

// ---------------------------------------------------------------------------
// Per-frame GNN (unchanged from R9-R12 — DS-count-optimized, verified).
// ---------------------------------------------------------------------------
__global__ __launch_bounds__(512, 2)
void gnn_kernel(const float* __restrict__ x, const float* __restrict__ ea_g,
                const float* __restrict__ W1, const float* __restrict__ a_src1,
                const float* __restrict__ a_dst1, const float* __restrict__ We1,
                const float* __restrict__ a_edge1, const float* __restrict__ b1,
                const float* __restrict__ W2, const float* __restrict__ a_src2,
                const float* __restrict__ a_dst2, const float* __restrict__ We2,
                const float* __restrict__ a_edge2, const float* __restrict__ b2,
                const float* __restrict__ Wg, const float* __restrict__ bg,
                float* __restrict__ embs)
{
  __shared__ float x_s[NN * FF];
  __shared__ float W1_s[FF * PP];
  __shared__ float ea_s[EE];
  __shared__ float hA_s[NN * PP];
  __shared__ float hB_s[NN * PP];
  __shared__ float as1_s[4 * NN];
  __shared__ float ad1_s[4 * NN];
  __shared__ float asrc1_s[PP], adst1_s[PP], asrc2_s[PP], adst2_s[PP];
  __shared__ float b1_s[PP], b2_s[PP], Wg_s[PP];
  __shared__ float as2_s[NN], ad2_s[NN];
  __shared__ __align__(16) float coefA_s[16 * 272];
  __shared__ float denA_s[16 * 4];
  __shared__ __align__(16) float coefB_s[16 * 68];
  __shared__ float denB_s[16];
  __shared__ float wed_s[8];
  __shared__ float attn_s[NN];

  const int tid = threadIdx.x;
  const int t = blockIdx.x;
  const int wave = tid >> 6, lane = tid & 63;

  for (int i = tid; i < NN * FF; i += 512) x_s[i] = x[t * NN * FF + i];
  for (int i = tid; i < FF * PP; i += 512) W1_s[i] = W1[i];
  for (int i = tid; i < EE; i += 512) ea_s[i] = ea_g[t * EE + i];
  if (tid < PP) {
    asrc1_s[tid] = a_src1[tid]; adst1_s[tid] = a_dst1[tid];
    asrc2_s[tid] = a_src2[tid]; adst2_s[tid] = a_dst2[tid];
    b1_s[tid] = b1[tid]; b2_s[tid] = b2[tid]; Wg_s[tid] = Wg[tid];
  }
  if (tid >= 128 && tid < 132) {
    const int h = tid - 128;
    float acc = 0.f;
    for (int c = 0; c < 32; ++c) acc += We1[h * 32 + c] * a_edge1[h * 32 + c];
    wed_s[h] = acc;
  }
  if (tid == 132) {
    float acc = 0.f;
    for (int c = 0; c < 128; ++c) acc += We2[c] * a_edge2[c];
    wed_s[4] = acc;
  }
  __syncthreads();

  {
    const int c = tid & 127, ib = tid >> 7;
    for (int q = 0; q < 16; ++q) {
      const int i = ib * 16 + q;
      float acc = 0.f;
#pragma unroll
      for (int f = 0; f < FF; ++f) acc += x_s[i * FF + f] * W1_s[f * PP + c];
      hA_s[i * PP + c] = acc;
    }
  }
  __syncthreads();

  {
    const int half = tid >> 8;
    const int tt2 = tid & 255;
    const int i = tt2 >> 2, h = tt2 & 3;
    const float* aw = half ? adst1_s : asrc1_s;
    float acc = 0.f;
    for (int cc = 0; cc < 32; ++cc) {
      const int c = (cc + tid) & 31;
      acc += hA_s[i * PP + h * 32 + c] * aw[h * 32 + c];
    }
    if (half) ad1_s[h * 64 + i] = acc; else as1_s[h * 64 + i] = acc;
  }
  __syncthreads();

  for (int g = 0; g < 4; ++g) {
#pragma unroll
    for (int r = 0; r < 2; ++r) {
      const int d = g * 16 + r * 8 + wave;
      const int dl = d & 15;
      float a0, a1, a2, a3;
      if (lane != d) {
        const int jj = lane * 63 + (d < lane ? d : d - 1);
        const float ev = ea_s[jj];
        a0 = as1_s[0 * 64 + lane] + ad1_s[0 * 64 + d] + ev * wed_s[0];
        a1 = as1_s[1 * 64 + lane] + ad1_s[1 * 64 + d] + ev * wed_s[1];
        a2 = as1_s[2 * 64 + lane] + ad1_s[2 * 64 + d] + ev * wed_s[2];
        a3 = as1_s[3 * 64 + lane] + ad1_s[3 * 64 + d] + ev * wed_s[3];
        a0 = a0 > 0.f ? a0 : 0.2f * a0;
        a1 = a1 > 0.f ? a1 : 0.2f * a1;
        a2 = a2 > 0.f ? a2 : 0.2f * a2;
        a3 = a3 > 0.f ? a3 : 0.2f * a3;
      } else { a0 = a1 = a2 = a3 = -1e30f; }
      const float m0 = allred_max(a0), m1 = allred_max(a1);
      const float m2 = allred_max(a2), m3 = allred_max(a3);
      const float p0 = (lane != d) ? __expf(a0 - m0) : 0.f;
      const float p1 = (lane != d) ? __expf(a1 - m1) : 0.f;
      const float p2 = (lane != d) ? __expf(a2 - m2) : 0.f;
      const float p3 = (lane != d) ? __expf(a3 - m3) : 0.f;
      const float s0 = allred_sum(p0), s1 = allred_sum(p1);
      const float s2 = allred_sum(p2), s3 = allred_sum(p3);
      coefA_s[dl * 272 + 0 * 68 + lane] = p0;
      coefA_s[dl * 272 + 1 * 68 + lane] = p1;
      coefA_s[dl * 272 + 2 * 68 + lane] = p2;
      coefA_s[dl * 272 + 3 * 68 + lane] = p3;
      if (lane == 0) {
        denA_s[dl * 4 + 0] = s0; denA_s[dl * 4 + 1] = s1;
        denA_s[dl * 4 + 2] = s2; denA_s[dl * 4 + 3] = s3;
      }
    }
    __syncthreads();
    {
      const int half = lane >> 5;
      const int dl = wave * 2 + half;
      const int d  = g * 16 + dl;
      const int c0 = (lane & 31) * 4;
      const int hh = c0 >> 5;
      const float* cfb = &coefA_s[dl * 272 + hh * 68];
      float ac0 = 0.f, ac1 = 0.f, ac2 = 0.f, ac3 = 0.f;
#pragma unroll 4
      for (int s = 0; s < 64; s += 4) {
        const float4 cf = *(const float4*)&cfb[s];
        const float4 h0 = *(const float4*)&hA_s[(s + 0) * PP + c0];
        ac0 += cf.x * h0.x; ac1 += cf.x * h0.y; ac2 += cf.x * h0.z; ac3 += cf.x * h0.w;
        const float4 h1v = *(const float4*)&hA_s[(s + 1) * PP + c0];
        ac0 += cf.y * h1v.x; ac1 += cf.y * h1v.y; ac2 += cf.y * h1v.z; ac3 += cf.y * h1v.w;
        const float4 h2v = *(const float4*)&hA_s[(s + 2) * PP + c0];
        ac0 += cf.z * h2v.x; ac1 += cf.z * h2v.y; ac2 += cf.z * h2v.z; ac3 += cf.z * h2v.w;
        const float4 h3v = *(const float4*)&hA_s[(s + 3) * PP + c0];
        ac0 += cf.w * h3v.x; ac1 += cf.w * h3v.y; ac2 += cf.w * h3v.z; ac3 += cf.w * h3v.w;
      }
      const float inv = 1.f / (denA_s[dl * 4 + hh] + 1e-16f);
      const float4 bv = *(const float4*)&b1_s[c0];
      float4 o;
      o.x = fmaxf(ac0 * inv + bv.x, 0.f);
      o.y = fmaxf(ac1 * inv + bv.y, 0.f);
      o.z = fmaxf(ac2 * inv + bv.z, 0.f);
      o.w = fmaxf(ac3 * inv + bv.w, 0.f);
      *(float4*)&hB_s[d * PP + c0] = o;
    }
    __syncthreads();
  }

  {
    const int cg = tid & 31, ig = tid >> 5;
    const int c0 = cg * 4, i0 = ig * 4;
    float acc[4][4];
#pragma unroll
    for (int ii = 0; ii < 4; ++ii)
#pragma unroll
      for (int cc = 0; cc < 4; ++cc) acc[ii][cc] = 0.f;
    for (int f0 = 0; f0 < 128; f0 += 4) {
      float4 wv0 = *(const float4*)&W2[(f0 + 0) * PP + c0];
      float4 wv1 = *(const float4*)&W2[(f0 + 1) * PP + c0];
      float4 wv2 = *(const float4*)&W2[(f0 + 2) * PP + c0];
      float4 wv3 = *(const float4*)&W2[(f0 + 3) * PP + c0];
#pragma unroll
      for (int ii = 0; ii < 4; ++ii) {
        const float4 hv = *(const float4*)&hB_s[(i0 + ii) * PP + f0];
        acc[ii][0] += hv.x * wv0.x + hv.y * wv1.x + hv.z * wv2.x + hv.w * wv3.x;
        acc[ii][1] += hv.x * wv0.y + hv.y * wv1.y + hv.z * wv2.y + hv.w * wv3.y;
        acc[ii][2] += hv.x * wv0.z + hv.y * wv1.z + hv.z * wv2.z + hv.w * wv3.z;
        acc[ii][3] += hv.x * wv0.w + hv.y * wv1.w + hv.z * wv2.w + hv.w * wv3.w;
      }
    }
#pragma unroll
    for (int ii = 0; ii < 4; ++ii) {
      float4 o; o.x = acc[ii][0]; o.y = acc[ii][1]; o.z = acc[ii][2]; o.w = acc[ii][3];
      *(float4*)&hA_s[(i0 + ii) * PP + c0] = o;
    }
  }
  __syncthreads();

  if (tid < 128) {
    const int i = tid >> 1, sel = tid & 1;
    const float* aw = sel ? adst2_s : asrc2_s;
    float acc = 0.f;
    for (int cc = 0; cc < 128; ++cc) {
      const int c = (cc + tid) & 127;
      acc += hA_s[i * PP + c] * aw[c];
    }
    if (sel) ad2_s[i] = acc; else as2_s[i] = acc;
  }
  __syncthreads();

  for (int g = 0; g < 4; ++g) {
#pragma unroll
    for (int r = 0; r < 2; ++r) {
      const int d = g * 16 + r * 8 + wave;
      const int dl = d & 15;
      float a;
      if (lane != d) {
        const int jj = lane * 63 + (d < lane ? d : d - 1);
        a = as2_s[lane] + ad2_s[d] + ea_s[jj] * wed_s[4];
        a = a > 0.f ? a : 0.2f * a;
      } else a = -1e30f;
      const float m = allred_max(a);
      const float p = (lane != d) ? __expf(a - m) : 0.f;
      const float ssum = allred_sum(p);
      coefB_s[dl * 68 + lane] = p;
      if (lane == 0) denB_s[dl] = ssum;
    }
    __syncthreads();
    {
      const int half = lane >> 5;
      const int dl = wave * 2 + half;
      const int d  = g * 16 + dl;
      const int c0 = (lane & 31) * 4;
      const float* cfb = &coefB_s[dl * 68];
      float ac0 = 0.f, ac1 = 0.f, ac2 = 0.f, ac3 = 0.f;
#pragma unroll 4
      for (int s = 0; s < 64; s += 4) {
        const float4 cf = *(const float4*)&cfb[s];
        const float4 h0 = *(const float4*)&hA_s[(s + 0) * PP + c0];
        ac0 += cf.x * h0.x; ac1 += cf.x * h0.y; ac2 += cf.x * h0.z; ac3 += cf.x * h0.w;
        const float4 h1v = *(const float4*)&hA_s[(s + 1) * PP + c0];
        ac0 += cf.y * h1v.x; ac1 += cf.y * h1v.y; ac2 += cf.y * h1v.z; ac3 += cf.y * h1v.w;
        const float4 h2v = *(const float4*)&hA_s[(s + 2) * PP + c0];
        ac0 += cf.z * h2v.x; ac1 += cf.z * h2v.y; ac2 += cf.z * h2v.z; ac3 += cf.z * h2v.w;
        const float4 h3v = *(const float4*)&hA_s[(s + 3) * PP + c0];
        ac0 += cf.w * h3v.x; ac1 += cf.w * h3v.y; ac2 += cf.w * h3v.z; ac3 += cf.w * h3v.w;
      }
      const float inv = 1.f / (denB_s[dl] + 1e-16f);
      const float4 bv = *(const float4*)&b2_s[c0];
      float4 o;
      o.x = fmaxf(ac0 * inv + bv.x, 0.f);
      o.y = fmaxf(ac1 * inv + bv.y, 0.f);
      o.z = fmaxf(ac2 * inv + bv.z, 0.f);
      o.w = fmaxf(ac3 * inv + bv.w, 0.f);
      *(float4*)&hB_s[d * PP + c0] = o;
    }
    __syncthreads();
  }

  if (tid < 64) {
    float acc = 0.f;
    for (int cc = 0; cc < 128; ++cc) {
      const int c = (cc + tid) & 127;
      acc += hB_s[tid * PP + c] * Wg_s[c];
    }
    const float logit = acc + bg[0];
    const float m = allred_max(logit);
    const float p = __expf(logit - m);
    const float ssum = allred_sum(p);
    attn_s[tid] = p / ssum;
  }
  __syncthreads();
  if (tid < 128) {
    const int c = tid;
    float acc = 0.f, mx = -1e30f;
    for (int i = 0; i < NN; ++i) {
      const float v = hB_s[i * PP + c];
      acc += attn_s[i] * v;
      mx = fmaxf(mx, v);
    }
    embs[t * 256 + c] = acc;
    embs[t * 256 + 128 + c] = mx;
  }
}

// ---------------------------------------------------------------------------
// Z projection. Forward Z written TRANSPOSED to [t][unit*4 + gate]
// (gate 0..3 = i,f,g,o) so the MFMA-LSTM's gate phase reads one coalesced
// float4 per unit. Zb keeps the old [gate*128+unit] layout (tail uses it).
// ---------------------------------------------------------------------------
__global__ __launch_bounds__(512, 2)
void zproj_kernel(const float* __restrict__ embs,
                  const float* __restrict__ Wih_f, const float* __restrict__ bih_f,
                  const float* __restrict__ bhh_f,
                  const float* __restrict__ Wih_b, const float* __restrict__ bih_b,
                  const float* __restrict__ bhh_b,
                  float* __restrict__ Z, float* __restrict__ Zb)
{
  __shared__ float e_s[256];
  const int t = blockIdx.x;
  const int j = threadIdx.x;
  const bool bwd = (t == TT);
  const int tsrc = bwd ? (TT - 1) : t;
  if (j < 256) e_s[j] = embs[tsrc * 256 + j];
  __syncthreads();
  const float* W = bwd ? Wih_b : Wih_f;
  float acc = bwd ? (bih_b[j] + bhh_b[j]) : (bih_f[j] + bhh_f[j]);
  const float4* Wr = (const float4*)(W + j * 256);
  const float4* er = (const float4*)e_s;
#pragma unroll 8
  for (int k = 0; k < 64; ++k) {
    const float4 w = Wr[k];
    const float4 e = er[k];
    acc += w.x * e.x + w.y * e.y + w.z * e.z + w.w * e.w;
  }
  if (bwd) Zb[j] = acc;
  else     Z[t * 512 + (j & 127) * 4 + (j >> 7)] = acc;   // [t][unit][gate]
}

// ---------------------------------------------------------------------------
// Forward LSTM recurrence via MFMA. R13 failed to compile: "+v" pins on
// uint4 are "tied indirect register inputs" the backend rejects. Fix: the
// 32 A-fragment dwords are 32 NAMED SCALAR unsigned (the exact pattern
// that compiled and stayed resident R7-R12); s16x8 MFMA operands are
// assembled in-loop via ext_vector brace-init + bit_cast.
// Per wave per step: 4 broadcast ds_read_b128 (h bf16, replicated across
// all 16 B-cols), 8x v_mfma_f32_16x16x32_bf16, in-register gate math,
// 2 ds_write_b16, ONE barrier. A-row map p -> (p&3)*128 + wave*8 + T*4 +
// (p>>2) makes each lane's 4 C-regs (m89 layout: row=(lane>>4)*4+reg) =
// {i,f,g,o} of unit wave*8 + T*4 + (lane>>4): gate math has NO cross-lane
// ops. A/B share the same (lane>>4, j) k-map -> dot product invariant.
// ---------------------------------------------------------------------------
__global__ __launch_bounds__(1024)
void lstm_kernel(const float* __restrict__ Zt, const float* __restrict__ Zb,
                 const float* __restrict__ Whh_f,
                 const float* __restrict__ Wo, const float* __restrict__ bo,
                 float* __restrict__ out)
{
  __shared__ __align__(16) unsigned h16_s[2][64];  // h as bf16x2, double-buffered
  __shared__ float h_s[128];
  __shared__ float hb_s[128];
  __shared__ float red_s[16];
  const int tid = threadIdx.x;
  const int wave = tid >> 6, lane = tid & 63;
  const int g16 = lane >> 4;            // k-group / row-group
  const int p_  = lane & 15;            // A-fragment row supplied by this lane
  const int u0 = wave * 8 + g16;        // tile0 unit owned by this lane's C regs
  const int u1 = u0 + 4;                // tile1 unit
  const int rowT0 = (p_ & 3) * 128 + wave * 8 + 0 + (p_ >> 2);
  const int rowT1 = (p_ & 3) * 128 + wave * 8 + 4 + (p_ >> 2);
  const float* rp0 = Whh_f + rowT0 * 128;
  const float* rp1 = Whh_f + rowT1 * 128;

  // A fragments as 32 named scalar dwords (pinnable, R8-proven pattern).
  // Tile T, chunk q: elems j=0..7 at k = q*32 + g16*8 + j.
#define LDW(nm, rp, q) \
  unsigned nm##x, nm##y, nm##z, nm##w; { \
    const float4 va = *(const float4*)&(rp)[(q) * 32 + g16 * 8]; \
    const float4 vb = *(const float4*)&(rp)[(q) * 32 + g16 * 8 + 4]; \
    nm##x = pk_bf16(va.x, va.y); nm##y = pk_bf16(va.z, va.w); \
    nm##z = pk_bf16(vb.x, vb.y); nm##w = pk_bf16(vb.z, vb.w); }
  LDW(a00, rp0, 0) LDW(a01, rp0, 1) LDW(a02, rp0, 2) LDW(a03, rp0, 3)
  LDW(a10, rp1, 0) LDW(a11, rp1, 1) LDW(a12, rp1, 2) LDW(a13, rp1, 3)
#undef LDW
  asm volatile("" : "+v"(a00x), "+v"(a00y), "+v"(a00z), "+v"(a00w),
                    "+v"(a01x), "+v"(a01y), "+v"(a01z), "+v"(a01w),
                    "+v"(a02x), "+v"(a02y), "+v"(a02z), "+v"(a02w),
                    "+v"(a03x), "+v"(a03y), "+v"(a03z), "+v"(a03w));
  asm volatile("" : "+v"(a10x), "+v"(a10y), "+v"(a10z), "+v"(a10w),
                    "+v"(a11x), "+v"(a11y), "+v"(a11z), "+v"(a11w),
                    "+v"(a12x), "+v"(a12y), "+v"(a12z), "+v"(a12w),
                    "+v"(a13x), "+v"(a13y), "+v"(a13z), "+v"(a13w));

  float c0 = 0.f, c1 = 0.f, h0 = 0.f, h1 = 0.f;
  if (tid < 64) { h16_s[0][tid] = 0u; h16_s[1][tid] = 0u; }
  __syncthreads();

#define MKA(nm) __builtin_bit_cast(s16x8, (u32x4){nm##x, nm##y, nm##z, nm##w})
  int pb = 0;
  for (int t = 0; t < TT; ++t) {
    const float4 z0 = *(const float4*)&Zt[t * 512 + u0 * 4];
    const float4 z1 = *(const float4*)&Zt[t * 512 + u1 * 4];
    // B fragments: chunk q needs h dwords [q*16 + g16*4 .. +3] (broadcast)
    const u32x4 b0 = *(const u32x4*)&h16_s[pb][ 0 + g16 * 4];
    const u32x4 b1 = *(const u32x4*)&h16_s[pb][16 + g16 * 4];
    const u32x4 b2 = *(const u32x4*)&h16_s[pb][32 + g16 * 4];
    const u32x4 b3 = *(const u32x4*)&h16_s[pb][48 + g16 * 4];
    f32x4 acc0 = {0.f, 0.f, 0.f, 0.f}, acc1 = {0.f, 0.f, 0.f, 0.f};
#define MM(A, B, C) C = __builtin_amdgcn_mfma_f32_16x16x32_bf16( \
    (A), __builtin_bit_cast(s16x8, B), C, 0, 0, 0)
    MM(MKA(a00), b0, acc0); MM(MKA(a10), b0, acc1);
    MM(MKA(a01), b1, acc0); MM(MKA(a11), b1, acc1);
    MM(MKA(a02), b2, acc0); MM(MKA(a12), b2, acc1);
    MM(MKA(a03), b3, acc0); MM(MKA(a13), b3, acc1);
#undef MM
    // lane's C regs = {i,f,g,o} preacts of units u0 (acc0) and u1 (acc1)
    const float i0 = sigm(acc0.x + z0.x), f0 = sigm(acc0.y + z0.y);
    const float g0 = tanh_fast(acc0.z + z0.z), o0 = sigm(acc0.w + z0.w);
    c0 = f0 * c0 + i0 * g0; h0 = o0 * tanh_fast(c0);
    const float i1 = sigm(acc1.x + z1.x), f1 = sigm(acc1.y + z1.y);
    const float g1 = tanh_fast(acc1.z + z1.z), o1 = sigm(acc1.w + z1.w);
    c1 = f1 * c1 + i1 * g1; h1 = o1 * tanh_fast(c1);
    // write new h (bf16) to the other buffer; col-0 lanes only
    if (p_ == 0) {
      unsigned short* hp = (unsigned short*)&h16_s[pb ^ 1][0];
      hp[u0] = (unsigned short)bf16rne(h0);
      hp[u1] = (unsigned short)bf16rne(h1);
    }
    __syncthreads();
    pb ^= 1;
  }
#undef MKA

  if (p_ == 0) { h_s[u0] = h0; h_s[u1] = h1; }

  // backward LSTM, first step only (h=c=0): elementwise on Zb (old layout)
  if (tid < 128) {
    const float gi = Zb[tid], gg = Zb[256 + tid], go = Zb[384 + tid];
    const float cb = sigm(gi) * tanh_fast(gg);
    hb_s[tid] = sigm(go) * tanh_fast(cb);
  }
  __syncthreads();

  // out = sigmoid(concat(h_f, h_b) · Wo + bo)
  float v = 0.f;
  if (tid < 128) v = h_s[tid] * Wo[tid];
  else if (tid < 256) v = hb_s[tid - 128] * Wo[tid];
  v = wave_sum64(v);
  if ((tid & 63) == 0) red_s[tid >> 6] = v;
  __syncthreads();
  if (tid == 0) {
    float sum = bo[0];
#pragma unroll
    for (int k = 0; k < 16; ++k) sum += red_s[k];
    out[0] = 1.f / (1.f + __expf(-sum));
  }
}

extern "C" void kernel_launch(void* const* d_in, const int* in_sizes, int n_in,
                              void* d_out, int out_size, void* d_ws, size_t ws_size,
                              hipStream_t stream) {
  const float* x       = (const float*)d_in[0];
  // d_in[1] = edge_index (int32) — complete digraph, indexed analytically
  const float* ea      = (const float*)d_in[2];
  const float* W1      = (const float*)d_in[3];
  const float* a_src1  = (const float*)d_in[4];
  const float* a_dst1  = (const float*)d_in[5];
  const float* We1     = (const float*)d_in[6];
  const float* a_edge1 = (const float*)d_in[7];
  const float* b1      = (const float*)d_in[8];
  const float* W2      = (const float*)d_in[9];
  const float* a_src2  = (const float*)d_in[10];
  const float* a_dst2  = (const float*)d_in[11];
  const float* We2     = (const float*)d_in[12];
  const float* a_edge2 = (const float*)d_in[13];
  const float* b2      = (const float*)d_in[14];
  const float* Wg      = (const float*)d_in[15];
  const float* bg      = (const float*)d_in[16];
  const float* Wih_f   = (const float*)d_in[17];
  const float* Whh_f   = (const float*)d_in[18];
  const float* bih_f   = (const float*)d_in[19];
  const float* bhh_f   = (const float*)d_in[20];
  const float* Wih_b   = (const float*)d_in[21];
  // d_in[22] = Whh_b — unused: backward LSTM contributes only its first step (h=0)
  const float* bih_b   = (const float*)d_in[23];
  const float* bhh_b   = (const float*)d_in[24];
  const float* Wo      = (const float*)d_in[25];
  const float* bo      = (const float*)d_in[26];
  float* out = (float*)d_out;

  float* embs = (float*)d_ws;            // 256*256 floats
  float* Z    = embs + 256 * 256;        // 256*512 floats (transposed layout)
  float* Zb   = Z + 256 * 512;           // 512 floats

  gnn_kernel<<<256, 512, 0, stream>>>(x, ea, W1, a_src1, a_dst1, We1, a_edge1, b1,
                                      W2, a_src2, a_dst2, We2, a_edge2, b2, Wg, bg, embs);
  zproj_kernel<<<257, 512, 0, stream>>>(embs, Wih_f, bih_f, bhh_f, Wih_b, bih_b, bhh_b, Z, Zb);
  lstm_kernel<<<1, 1024, 0, stream>>>(Z, Zb, Whh_f, Wo, bo, out);
}

// Round 15
// 260.482 us; speedup vs baseline: 1.8257x; 1.8257x over previous
//
#include <hip/hip_runtime.h>
#include <math.h>

#define NN 64      // nodes
#define TT 256     // frames
#define FF 13      // input features
#define EE 4032    // edges (complete digraph)
#define PP 128     // pooling channels / GAT1 out
#define HH 128     // hidden

typedef float f32x4 __attribute__((ext_vector_type(4)));
typedef _Float16 f16x2 __attribute__((ext_vector_type(2)));

__device__ __forceinline__ float wave_sum64(float v) {
#pragma unroll
  for (int off = 32; off > 0; off >>= 1) v += __shfl_xor(v, off, 64);
  return v;
}
__device__ __forceinline__ float sigm(float x) { return 1.f / (1.f + __expf(-x)); }
__device__ __forceinline__ float tanh_fast(float x) { return 1.f - 2.f / (__expf(2.f * x) + 1.f); }

// ---- DPP / lane helpers (VALU pipe) ----
#define ROTF(x, N) __builtin_bit_cast(float, __builtin_amdgcn_mov_dpp( \
    __builtin_bit_cast(int, x), 0x120 + (N), 0xF, 0xF, true))
__device__ __forceinline__ float rdlane(float v, int l) {
  return __builtin_bit_cast(float, __builtin_amdgcn_readlane(__builtin_bit_cast(int, v), l));
}
__device__ __forceinline__ float allred_max(float v) {
  v = fmaxf(v, ROTF(v, 1)); v = fmaxf(v, ROTF(v, 2));
  v = fmaxf(v, ROTF(v, 4)); v = fmaxf(v, ROTF(v, 8));
  return fmaxf(fmaxf(rdlane(v, 0), rdlane(v, 16)),
               fmaxf(rdlane(v, 32), rdlane(v, 48)));
}
__device__ __forceinline__ float allred_sum(float v) {
  v += ROTF(v, 1); v += ROTF(v, 2); v += ROTF(v, 4); v += ROTF(v, 8);
  return (rdlane(v, 0) + rdlane(v, 16)) + (rdlane(v, 32) + rdlane(v, 48));
}

// pack two fp32 -> one dword of two f16 (round-toward-zero HW op)
__device__ __forceinline__ unsigned pk_f16(float lo, float hi) {
  unsigned u;
  asm("v_cvt_pkrtz_f16_f32 %0, %1, %2" : "=v"(u) : "v"(lo), "v"(hi));
  return u;
}
// fp32 += dot2(f16x2, f16x2)
__device__ __forceinline__ float fdot2u(unsigned h, unsigned w, float acc) {
#if __has_builtin(__builtin_amdgcn_fdot2)
  return __builtin_amdgcn_fdot2(__builtin_bit_cast(f16x2, h),
                                __builtin_bit_cast(f16x2, w), acc, false);
#else
  const f16x2 a = __builtin_bit_cast(f16x2, h);
  const f16x2 b = __builtin_bit_cast(f16x2, b);
  return acc + (float)a.x * (float)b.x + (float)a.y * (float)b.y;
#endif
}
__device__ __forceinline__ float ror1(float x) {
  return __builtin_bit_cast(float, __builtin_amdgcn_mov_dpp(
      __builtin_bit_cast(int, x), 0x121, 0xF, 0xF, true));
}
__device__ __forceinline__ float qswap1(float x) {
  return __builtin_bit_cast(float, __builtin_amdgcn_mov_dpp(
      __builtin_bit_cast(int, x), 0xB1, 0xF, 0xF, true));
}

// ---------------------------------------------------------------------------
// Per-frame GNN (R9 version — DS-count-optimized, best measured, verified).
// ---------------------------------------------------------------------------
__global__ __launch_bounds__(512, 2)
void gnn_kernel(const float* __restrict__ x, const float* __restrict__ ea_g,
                const float* __restrict__ W1, const float* __restrict__ a_src1,
                const float* __restrict__ a_dst1, const float* __restrict__ We1,
                const float* __restrict__ a_edge1, const float* __restrict__ b1,
                const float* __restrict__ W2, const float* __restrict__ a_src2,
                const float* __restrict__ a_dst2, const float* __restrict__ We2,
                const float* __restrict__ a_edge2, const float* __restrict__ b2,
                const float* __restrict__ Wg, const float* __restrict__ bg,
                float* __restrict__ embs)
{
  __shared__ float x_s[NN * FF];
  __shared__ float W1_s[FF * PP];
  __shared__ float ea_s[EE];
  __shared__ float hA_s[NN * PP];
  __shared__ float hB_s[NN * PP];
  __shared__ float as1_s[4 * NN];
  __shared__ float ad1_s[4 * NN];
  __shared__ float asrc1_s[PP], adst1_s[PP], asrc2_s[PP], adst2_s[PP];
  __shared__ float b1_s[PP], b2_s[PP], Wg_s[PP];
  __shared__ float as2_s[NN], ad2_s[NN];
  __shared__ __align__(16) float coefA_s[16 * 272];
  __shared__ float denA_s[16 * 4];
  __shared__ __align__(16) float coefB_s[16 * 68];
  __shared__ float denB_s[16];
  __shared__ float wed_s[8];
  __shared__ float attn_s[NN];

  const int tid = threadIdx.x;
  const int t = blockIdx.x;
  const int wave = tid >> 6, lane = tid & 63;

  for (int i = tid; i < NN * FF; i += 512) x_s[i] = x[t * NN * FF + i];
  for (int i = tid; i < FF * PP; i += 512) W1_s[i] = W1[i];
  for (int i = tid; i < EE; i += 512) ea_s[i] = ea_g[t * EE + i];
  if (tid < PP) {
    asrc1_s[tid] = a_src1[tid]; adst1_s[tid] = a_dst1[tid];
    asrc2_s[tid] = a_src2[tid]; adst2_s[tid] = a_dst2[tid];
    b1_s[tid] = b1[tid]; b2_s[tid] = b2[tid]; Wg_s[tid] = Wg[tid];
  }
  if (tid >= 128 && tid < 132) {
    const int h = tid - 128;
    float acc = 0.f;
    for (int c = 0; c < 32; ++c) acc += We1[h * 32 + c] * a_edge1[h * 32 + c];
    wed_s[h] = acc;
  }
  if (tid == 132) {
    float acc = 0.f;
    for (int c = 0; c < 128; ++c) acc += We2[c] * a_edge2[c];
    wed_s[4] = acc;
  }
  __syncthreads();

  {
    const int c = tid & 127, ib = tid >> 7;
    for (int q = 0; q < 16; ++q) {
      const int i = ib * 16 + q;
      float acc = 0.f;
#pragma unroll
      for (int f = 0; f < FF; ++f) acc += x_s[i * FF + f] * W1_s[f * PP + c];
      hA_s[i * PP + c] = acc;
    }
  }
  __syncthreads();

  {
    const int half = tid >> 8;
    const int tt2 = tid & 255;
    const int i = tt2 >> 2, h = tt2 & 3;
    const float* aw = half ? adst1_s : asrc1_s;
    float acc = 0.f;
    for (int cc = 0; cc < 32; ++cc) {
      const int c = (cc + tid) & 31;
      acc += hA_s[i * PP + h * 32 + c] * aw[h * 32 + c];
    }
    if (half) ad1_s[h * 64 + i] = acc; else as1_s[h * 64 + i] = acc;
  }
  __syncthreads();

  for (int g = 0; g < 4; ++g) {
#pragma unroll
    for (int r = 0; r < 2; ++r) {
      const int d = g * 16 + r * 8 + wave;
      const int dl = d & 15;
      float a0, a1, a2, a3;
      if (lane != d) {
        const int jj = lane * 63 + (d < lane ? d : d - 1);
        const float ev = ea_s[jj];
        a0 = as1_s[0 * 64 + lane] + ad1_s[0 * 64 + d] + ev * wed_s[0];
        a1 = as1_s[1 * 64 + lane] + ad1_s[1 * 64 + d] + ev * wed_s[1];
        a2 = as1_s[2 * 64 + lane] + ad1_s[2 * 64 + d] + ev * wed_s[2];
        a3 = as1_s[3 * 64 + lane] + ad1_s[3 * 64 + d] + ev * wed_s[3];
        a0 = a0 > 0.f ? a0 : 0.2f * a0;
        a1 = a1 > 0.f ? a1 : 0.2f * a1;
        a2 = a2 > 0.f ? a2 : 0.2f * a2;
        a3 = a3 > 0.f ? a3 : 0.2f * a3;
      } else { a0 = a1 = a2 = a3 = -1e30f; }
      const float m0 = allred_max(a0), m1 = allred_max(a1);
      const float m2 = allred_max(a2), m3 = allred_max(a3);
      const float p0 = (lane != d) ? __expf(a0 - m0) : 0.f;
      const float p1 = (lane != d) ? __expf(a1 - m1) : 0.f;
      const float p2 = (lane != d) ? __expf(a2 - m2) : 0.f;
      const float p3 = (lane != d) ? __expf(a3 - m3) : 0.f;
      const float s0 = allred_sum(p0), s1 = allred_sum(p1);
      const float s2 = allred_sum(p2), s3 = allred_sum(p3);
      coefA_s[dl * 272 + 0 * 68 + lane] = p0;
      coefA_s[dl * 272 + 1 * 68 + lane] = p1;
      coefA_s[dl * 272 + 2 * 68 + lane] = p2;
      coefA_s[dl * 272 + 3 * 68 + lane] = p3;
      if (lane == 0) {
        denA_s[dl * 4 + 0] = s0; denA_s[dl * 4 + 1] = s1;
        denA_s[dl * 4 + 2] = s2; denA_s[dl * 4 + 3] = s3;
      }
    }
    __syncthreads();
    {
      const int half = lane >> 5;
      const int dl = wave * 2 + half;
      const int d  = g * 16 + dl;
      const int c0 = (lane & 31) * 4;
      const int hh = c0 >> 5;
      const float* cfb = &coefA_s[dl * 272 + hh * 68];
      float ac0 = 0.f, ac1 = 0.f, ac2 = 0.f, ac3 = 0.f;
#pragma unroll 4
      for (int s = 0; s < 64; s += 4) {
        const float4 cf = *(const float4*)&cfb[s];
        const float4 h0 = *(const float4*)&hA_s[(s + 0) * PP + c0];
        ac0 += cf.x * h0.x; ac1 += cf.x * h0.y; ac2 += cf.x * h0.z; ac3 += cf.x * h0.w;
        const float4 h1v = *(const float4*)&hA_s[(s + 1) * PP + c0];
        ac0 += cf.y * h1v.x; ac1 += cf.y * h1v.y; ac2 += cf.y * h1v.z; ac3 += cf.y * h1v.w;
        const float4 h2v = *(const float4*)&hA_s[(s + 2) * PP + c0];
        ac0 += cf.z * h2v.x; ac1 += cf.z * h2v.y; ac2 += cf.z * h2v.z; ac3 += cf.z * h2v.w;
        const float4 h3v = *(const float4*)&hA_s[(s + 3) * PP + c0];
        ac0 += cf.w * h3v.x; ac1 += cf.w * h3v.y; ac2 += cf.w * h3v.z; ac3 += cf.w * h3v.w;
      }
      const float inv = 1.f / (denA_s[dl * 4 + hh] + 1e-16f);
      const float4 bv = *(const float4*)&b1_s[c0];
      float4 o;
      o.x = fmaxf(ac0 * inv + bv.x, 0.f);
      o.y = fmaxf(ac1 * inv + bv.y, 0.f);
      o.z = fmaxf(ac2 * inv + bv.z, 0.f);
      o.w = fmaxf(ac3 * inv + bv.w, 0.f);
      *(float4*)&hB_s[d * PP + c0] = o;
    }
    __syncthreads();
  }

  {
    const int cg = tid & 31, ig = tid >> 5;
    const int c0 = cg * 4, i0 = ig * 4;
    float acc[4][4];
#pragma unroll
    for (int ii = 0; ii < 4; ++ii)
#pragma unroll
      for (int cc = 0; cc < 4; ++cc) acc[ii][cc] = 0.f;
    for (int f0 = 0; f0 < 128; f0 += 4) {
      float4 wv0 = *(const float4*)&W2[(f0 + 0) * PP + c0];
      float4 wv1 = *(const float4*)&W2[(f0 + 1) * PP + c0];
      float4 wv2 = *(const float4*)&W2[(f0 + 2) * PP + c0];
      float4 wv3 = *(const float4*)&W2[(f0 + 3) * PP + c0];
#pragma unroll
      for (int ii = 0; ii < 4; ++ii) {
        const float4 hv = *(const float4*)&hB_s[(i0 + ii) * PP + f0];
        acc[ii][0] += hv.x * wv0.x + hv.y * wv1.x + hv.z * wv2.x + hv.w * wv3.x;
        acc[ii][1] += hv.x * wv0.y + hv.y * wv1.y + hv.z * wv2.y + hv.w * wv3.y;
        acc[ii][2] += hv.x * wv0.z + hv.y * wv1.z + hv.z * wv2.z + hv.w * wv3.z;
        acc[ii][3] += hv.x * wv0.w + hv.y * wv1.w + hv.z * wv2.w + hv.w * wv3.w;
      }
    }
#pragma unroll
    for (int ii = 0; ii < 4; ++ii) {
      float4 o; o.x = acc[ii][0]; o.y = acc[ii][1]; o.z = acc[ii][2]; o.w = acc[ii][3];
      *(float4*)&hA_s[(i0 + ii) * PP + c0] = o;
    }
  }
  __syncthreads();

  if (tid < 128) {
    const int i = tid >> 1, sel = tid & 1;
    const float* aw = sel ? adst2_s : asrc2_s;
    float acc = 0.f;
    for (int cc = 0; cc < 128; ++cc) {
      const int c = (cc + tid) & 127;
      acc += hA_s[i * PP + c] * aw[c];
    }
    if (sel) ad2_s[i] = acc; else as2_s[i] = acc;
  }
  __syncthreads();

  for (int g = 0; g < 4; ++g) {
#pragma unroll
    for (int r = 0; r < 2; ++r) {
      const int d = g * 16 + r * 8 + wave;
      const int dl = d & 15;
      float a;
      if (lane != d) {
        const int jj = lane * 63 + (d < lane ? d : d - 1);
        a = as2_s[lane] + ad2_s[d] + ea_s[jj] * wed_s[4];
        a = a > 0.f ? a : 0.2f * a;
      } else a = -1e30f;
      const float m = allred_max(a);
      const float p = (lane != d) ? __expf(a - m) : 0.f;
      const float ssum = allred_sum(p);
      coefB_s[dl * 68 + lane] = p;
      if (lane == 0) denB_s[dl] = ssum;
    }
    __syncthreads();
    {
      const int half = lane >> 5;
      const int dl = wave * 2 + half;
      const int d  = g * 16 + dl;
      const int c0 = (lane & 31) * 4;
      const float* cfb = &coefB_s[dl * 68];
      float ac0 = 0.f, ac1 = 0.f, ac2 = 0.f, ac3 = 0.f;
#pragma unroll 4
      for (int s = 0; s < 64; s += 4) {
        const float4 cf = *(const float4*)&cfb[s];
        const float4 h0 = *(const float4*)&hA_s[(s + 0) * PP + c0];
        ac0 += cf.x * h0.x; ac1 += cf.x * h0.y; ac2 += cf.x * h0.z; ac3 += cf.x * h0.w;
        const float4 h1v = *(const float4*)&hA_s[(s + 1) * PP + c0];
        ac0 += cf.y * h1v.x; ac1 += cf.y * h1v.y; ac2 += cf.y * h1v.z; ac3 += cf.y * h1v.w;
        const float4 h2v = *(const float4*)&hA_s[(s + 2) * PP + c0];
        ac0 += cf.z * h2v.x; ac1 += cf.z * h2v.y; ac2 += cf.z * h2v.z; ac3 += cf.z * h2v.w;
        const float4 h3v = *(const float4*)&hA_s[(s + 3) * PP + c0];
        ac0 += cf.w * h3v.x; ac1 += cf.w * h3v.y; ac2 += cf.w * h3v.z; ac3 += cf.w * h3v.w;
      }
      const float inv = 1.f / (denB_s[dl] + 1e-16f);
      const float4 bv = *(const float4*)&b2_s[c0];
      float4 o;
      o.x = fmaxf(ac0 * inv + bv.x, 0.f);
      o.y = fmaxf(ac1 * inv + bv.y, 0.f);
      o.z = fmaxf(ac2 * inv + bv.z, 0.f);
      o.w = fmaxf(ac3 * inv + bv.w, 0.f);
      *(float4*)&hB_s[d * PP + c0] = o;
    }
    __syncthreads();
  }

  if (tid < 64) {
    float acc = 0.f;
    for (int cc = 0; cc < 128; ++cc) {
      const int c = (cc + tid) & 127;
      acc += hB_s[tid * PP + c] * Wg_s[c];
    }
    const float logit = acc + bg[0];
    const float m = allred_max(logit);
    const float p = __expf(logit - m);
    const float ssum = allred_sum(p);
    attn_s[tid] = p / ssum;
  }
  __syncthreads();
  if (tid < 128) {
    const int c = tid;
    float acc = 0.f, mx = -1e30f;
    for (int i = 0; i < NN; ++i) {
      const float v = hB_s[i * PP + c];
      acc += attn_s[i] * v;
      mx = fmaxf(mx, v);
    }
    embs[t * 256 + c] = acc;
    embs[t * 256 + 128 + c] = mx;
  }
}

// ---------------------------------------------------------------------------
// Z[t][j] and Zb[j] projections (original layout)
// ---------------------------------------------------------------------------
__global__ __launch_bounds__(512, 2)
void zproj_kernel(const float* __restrict__ embs,
                  const float* __restrict__ Wih_f, const float* __restrict__ bih_f,
                  const float* __restrict__ bhh_f,
                  const float* __restrict__ Wih_b, const float* __restrict__ bih_b,
                  const float* __restrict__ bhh_b,
                  float* __restrict__ Z, float* __restrict__ Zb)
{
  __shared__ float e_s[256];
  const int t = blockIdx.x;
  const int j = threadIdx.x;
  const bool bwd = (t == TT);
  const int tsrc = bwd ? (TT - 1) : t;
  if (j < 256) e_s[j] = embs[tsrc * 256 + j];
  __syncthreads();
  const float* W = bwd ? Wih_b : Wih_f;
  float acc = bwd ? (bih_b[j] + bhh_b[j]) : (bih_f[j] + bhh_f[j]);
  const float4* Wr = (const float4*)(W + j * 256);
  const float4* er = (const float4*)e_s;
#pragma unroll 8
  for (int k = 0; k < 64; ++k) {
    const float4 w = Wr[k];
    const float4 e = er[k];
    acc += w.x * e.x + w.y * e.y + w.z * e.z + w.w * e.w;
  }
  if (bwd) Zb[j] = acc; else Z[t * 512 + j] = acc;
}

// ---------------------------------------------------------------------------
// Forward LSTM recurrence -- R8 version (best measured: 196us/step-kernel,
// weights VGPR-resident at 40 VGPR, no scratch). Systolic ring over 16-lane
// groups; f16 weights in 32 packed dwords; split-k across 2 thread groups.
// R7-R14 measured floor: 8 structurally distinct variants (VALU ring, pk_fma,
// same-wave combine, one-barrier quad-gates, MFMA port) all land >=765ns/step
// -- the serial recurrence's latency chain {ds_read ~120cy + matvec chain +
// inter-wave sync} is the binding constraint, not instruction throughput.
// ---------------------------------------------------------------------------
__global__ __launch_bounds__(1024)
void lstm_kernel(const float* __restrict__ Z, const float* __restrict__ Zb,
                 const float* __restrict__ Whh_f,
                 const float* __restrict__ Wo, const float* __restrict__ bo,
                 float* __restrict__ out)
{
  __shared__ float h_s[128];
  __shared__ __align__(16) unsigned h16_s[64];
  __shared__ float p_s[1024];
  __shared__ float hb_s[128];
  __shared__ float red_s[16];
  const int tid = threadIdx.x;
  const int j = tid & 511;
  const int s = tid >> 9;
  const int m = tid & 15;
  const int j0 = j & ~15;

  const float* wbase = Whh_f + s * 64 + 4 * m;
#define LWR(r) \
  unsigned wa##r, wb##r; { \
    const float4 v = *(const float4*)(wbase + (j0 + ((m - (r)) & 15)) * 128); \
    wa##r = pk_f16(v.x, v.y); wb##r = pk_f16(v.z, v.w); }
  LWR(0)  LWR(1)  LWR(2)  LWR(3)  LWR(4)  LWR(5)  LWR(6)  LWR(7)
  LWR(8)  LWR(9)  LWR(10) LWR(11) LWR(12) LWR(13) LWR(14) LWR(15)
#undef LWR
  asm volatile("" : "+v"(wa0),  "+v"(wb0),  "+v"(wa1),  "+v"(wb1),
                    "+v"(wa2),  "+v"(wb2),  "+v"(wa3),  "+v"(wb3),
                    "+v"(wa4),  "+v"(wb4),  "+v"(wa5),  "+v"(wb5),
                    "+v"(wa6),  "+v"(wb6),  "+v"(wa7),  "+v"(wb7));
  asm volatile("" : "+v"(wa8),  "+v"(wb8),  "+v"(wa9),  "+v"(wb9),
                    "+v"(wa10), "+v"(wb10), "+v"(wa11), "+v"(wb11),
                    "+v"(wa12), "+v"(wb12), "+v"(wa13), "+v"(wb13),
                    "+v"(wa14), "+v"(wb14), "+v"(wa15), "+v"(wb15));

  float c = 0.f;
  if (tid < 128) h_s[tid] = 0.f;
  if (tid < 64) h16_s[tid] = 0u;
  __syncthreads();

  float zcur = (s == 0) ? Z[j] : 0.f;
  for (int t = 0; t < TT; ++t) {
    const float znext = (s == 0 && t < TT - 1) ? Z[(t + 1) * 512 + j] : 0.f;
    const uint2 hd = *(const uint2*)&h16_s[s * 32 + 2 * m];
    float acc = 0.f;
#define STEP(r) \
    acc = fdot2u(hd.x, wa##r, acc); \
    acc = fdot2u(hd.y, wb##r, acc); \
    acc = ror1(acc);
    STEP(0)  STEP(1)  STEP(2)  STEP(3)  STEP(4)  STEP(5)  STEP(6)  STEP(7)
    STEP(8)  STEP(9)  STEP(10) STEP(11) STEP(12) STEP(13) STEP(14) STEP(15)
#undef STEP
    p_s[tid] = acc + zcur;
    __syncthreads();
    if (tid < 128) {
      const float gi = p_s[tid]       + p_s[512 + tid];
      const float gf = p_s[128 + tid] + p_s[640 + tid];
      const float gg = p_s[256 + tid] + p_s[768 + tid];
      const float go = p_s[384 + tid] + p_s[896 + tid];
      c = sigm(gf) * c + sigm(gi) * tanh_fast(gg);
      const float hnew = sigm(go) * tanh_fast(c);
      h_s[tid] = hnew;
      const float hnb = qswap1(hnew);
      if (!(tid & 1)) h16_s[tid >> 1] = pk_f16(hnew, hnb);
    }
    __syncthreads();
    zcur = znext;
  }

  if (tid < 128) {
    const float gi = Zb[tid], gg = Zb[256 + tid], go = Zb[384 + tid];
    const float cb = sigm(gi) * tanh_fast(gg);
    hb_s[tid] = sigm(go) * tanh_fast(cb);
  }
  __syncthreads();

  float v = 0.f;
  if (tid < 128) v = h_s[tid] * Wo[tid];
  else if (tid < 256) v = hb_s[tid - 128] * Wo[tid];
  v = wave_sum64(v);
  if ((tid & 63) == 0) red_s[tid >> 6] = v;
  __syncthreads();
  if (tid == 0) {
    float sum = bo[0];
#pragma unroll
    for (int k = 0; k < 16; ++k) sum += red_s[k];
    out[0] = 1.f / (1.f + __expf(-sum));
  }
}

extern "C" void kernel_launch(void* const* d_in, const int* in_sizes, int n_in,
                              void* d_out, int out_size, void* d_ws, size_t ws_size,
                              hipStream_t stream) {
  const float* x       = (const float*)d_in[0];
  // d_in[1] = edge_index (int32) — complete digraph, indexed analytically
  const float* ea      = (const float*)d_in[2];
  const float* W1      = (const float*)d_in[3];
  const float* a_src1  = (const float*)d_in[4];
  const float* a_dst1  = (const float*)d_in[5];
  const float* We1     = (const float*)d_in[6];
  const float* a_edge1 = (const float*)d_in[7];
  const float* b1      = (const float*)d_in[8];
  const float* W2      = (const float*)d_in[9];
  const float* a_src2  = (const float*)d_in[10];
  const float* a_dst2  = (const float*)d_in[11];
  const float* We2     = (const float*)d_in[12];
  const float* a_edge2 = (const float*)d_in[13];
  const float* b2      = (const float*)d_in[14];
  const float* Wg      = (const float*)d_in[15];
  const float* bg      = (const float*)d_in[16];
  const float* Wih_f   = (const float*)d_in[17];
  const float* Whh_f   = (const float*)d_in[18];
  const float* bih_f   = (const float*)d_in[19];
  const float* bhh_f   = (const float*)d_in[20];
  const float* Wih_b   = (const float*)d_in[21];
  // d_in[22] = Whh_b — unused: backward LSTM contributes only its first step (h=0)
  const float* bih_b   = (const float*)d_in[23];
  const float* bhh_b   = (const float*)d_in[24];
  const float* Wo      = (const float*)d_in[25];
  const float* bo      = (const float*)d_in[26];
  float* out = (float*)d_out;

  float* embs = (float*)d_ws;            // 256*256 floats
  float* Z    = embs + 256 * 256;        // 256*512 floats
  float* Zb   = Z + 256 * 512;           // 512 floats

  gnn_kernel<<<256, 512, 0, stream>>>(x, ea, W1, a_src1, a_dst1, We1, a_edge1, b1,
                                      W2, a_src2, a_dst2, We2, a_edge2, b2, Wg, bg, embs);
  zproj_kernel<<<257, 512, 0, stream>>>(embs, Wih_f, bih_f, bhh_f, Wih_b, bih_b, bhh_b, Z, Zb);
  lstm_kernel<<<1, 1024, 0, stream>>>(Z, Zb, Whh_f, Wo, bo, out);
}